// Round 15
// baseline (801.586 us; speedup 1.0000x reference)
//
#include <hip/hip_runtime.h>
#include <hip/hip_cooperative_groups.h>
#include <stdint.h>

namespace cg = cooperative_groups;

#define NPIX  131072      // B*H*W = 2*256*256
#define HW    65536       // H*W
#define CCH   256         // channels
#define NSEG  21
#define NROLL 20          // NSEG-1
#define NBLK  512

typedef float f32x2 __attribute__((ext_vector_type(2)));
typedef __fp16 half2t __attribute__((ext_vector_type(2)));

// ---------- helpers ----------
__device__ __forceinline__ uint64_t rng64(uint32_t i, uint32_t q, uint32_t j) {
  uint64_t x = ((uint64_t)((i << 8) | q) << 32) | (uint64_t)(j * 0x9E3779B1u);
  x ^= 0xD1B54A32D192ED03ULL;
  x += 0x9E3779B97F4A7C15ULL;
  x = (x ^ (x >> 30)) * 0xBF58476D1CE4E5B9ULL;
  x = (x ^ (x >> 27)) * 0x94D049BB133111EBULL;
  return x ^ (x >> 31);
}

__device__ __forceinline__ float fdot2h(half2t a, half2t b, float c) {
  return __builtin_amdgcn_fdot2(a, b, c, false);
}

// decode 16 fp8 (one uint4) -> 8 half2 (fp8 e4m3 exact in f16; RTZ exact)
__device__ __forceinline__ void dec16(uint4 w, half2t* nx) {
  uint32_t dw[4] = { w.x, w.y, w.z, w.w };
#pragma unroll
  for (int d = 0; d < 4; ++d) {
    f32x2 lo = __builtin_amdgcn_cvt_pk_f32_fp8((int)dw[d], false);
    f32x2 hi = __builtin_amdgcn_cvt_pk_f32_fp8((int)dw[d], true);
    nx[d * 2 + 0] = __builtin_amdgcn_cvt_pkrtz(lo.x, lo.y);
    nx[d * 2 + 1] = __builtin_amdgcn_cvt_pkrtz(hi.x, hi.y);
  }
}

__device__ __forceinline__ uint32_t pack4fp8(float a, float b, float c, float d) {
  uint32_t w = 0;
  w = (uint32_t)__builtin_amdgcn_cvt_pk_fp8_f32(a, b, (int)w, false);
  w = (uint32_t)__builtin_amdgcn_cvt_pk_fp8_f32(c, d, (int)w, true);
  return w;
}

// ---------- the whole loss as ONE cooperative kernel ----------
__global__ __launch_bounds__(256, 2) void reco_mega(
    const float* __restrict__ rep, const int* __restrict__ label,
    const float* __restrict__ mask, const float* __restrict__ prob,
    uint8_t* __restrict__ f8, float* __restrict__ norms,
    int* __restrict__ labh, int* __restrict__ list, int* __restrict__ bc,
    float* __restrict__ proto, float* __restrict__ protoN,
    int* __restrict__ counts, int* __restrict__ hardc, int* __restrict__ offs,
    int* __restrict__ cur_h, int* __restrict__ cur_e,
    float* __restrict__ cdf, float* __restrict__ seg_sum,
    float* __restrict__ out) {
  cg::grid_group grid = cg::this_grid();
  const int bid = blockIdx.x;
  const int t = threadIdx.x;
  __shared__ __align__(16) char SM[34048];

  // ===== P1: flags + per-block count partials (col-major) + zero accumulators =====
  {
    int row = bid;                 // b*H + h (512 rows)
    int b = row >> 8, h = row & 255;
    int n = row * 256 + t;
    if (row < 6) {                 // proto(1344 f4) + segsum(8 f4) = 1352 float4
      int idx = row * 256 + t;
      if (idx < 1352) ((float4*)proto)[idx] = make_float4(0.f, 0.f, 0.f, 0.f);
    }
    int lab = label[n];
    bool ignore = lab > NSEG - 1;
    if (ignore) lab = 0;
    float mval = ignore ? 0.f : mask[n];
    bool valid = mval > 0.f;
    float p_lab = prob[(((size_t)b * NSEG + lab) * 256 + h) * 256 + t];
    bool hard = valid && (p_lab < 1.0f);
    labh[n] = lab | (hard ? 32 : 0) | (valid ? 64 : 0);

    int* cpart = (int*)SM;         // [21]
    int* hpart = (int*)SM + 24;    // [21]
    if (t < NSEG) { cpart[t] = 0; hpart[t] = 0; }
    __syncthreads();
    if (valid) { atomicAdd(&cpart[lab], 1); if (hard) atomicAdd(&hpart[lab], 1); }
    __syncthreads();
    if (t < NSEG) {
      bc[t * 512 + row] = cpart[t];
      bc[(24 + t) * 512 + row] = hpart[t];
    }
  }
  __threadfence();
  grid.sync();

  // ===== P2: reduce partials -> counts/hardc/offs/cursors (block 0) =====
  if (bid == 0) {
    int wave = t >> 6, lane = t & 63;
    int* sums = (int*)SM;          // [42]
    for (int c = wave; c < 42; c += 4) {
      int col = (c < 21) ? c : c + 3;
      const int* p = bc + col * 512 + lane * 8;
      int s = 0;
#pragma unroll
      for (int j = 0; j < 8; ++j) s += p[j];
#pragma unroll
      for (int o = 32; o >= 1; o >>= 1) s += __shfl_xor(s, o);
      if (lane == 0) sums[c] = s;
    }
    __syncthreads();
    if (t == 0) {
      int o = 0;
      for (int s = 0; s < NSEG; ++s) {
        counts[s] = sums[s];
        hardc[s] = sums[21 + s];
        offs[s] = o;
        cur_h[s] = o;
        cur_e[s] = o + sums[21 + s];
        o += sums[s];
      }
      offs[NSEG] = o;
    }
  }
  __threadfence();
  grid.sync();

  // ===== P3: segment-grouped pixel list, hard-first =====
  {
    int n = bid * 256 + t;
    int* lcnt = (int*)SM;          // [42]
    int* lbase = (int*)SM + 48;    // [42]
    if (t < 2 * NSEG) lcnt[t] = 0;
    __syncthreads();
    int v = labh[n];
    int lab = v & 31;
    bool hard = (v & 32) != 0;
    bool valid = (v & 64) != 0;
    int bucket = lab + (hard ? 0 : NSEG);
    int rank = 0;
    if (valid) rank = atomicAdd(&lcnt[bucket], 1);
    __syncthreads();
    if (t < 2 * NSEG) {
      int c = lcnt[t];
      lbase[t] = c ? atomicAdd((t < NSEG) ? &cur_h[t] : &cur_e[t - NSEG], c) : 0;
    }
    __syncthreads();
    if (valid) list[lbase[bucket] + rank] = n;
  }
  __threadfence();
  grid.sync();

  // ===== P4: transpose + norm + fp8 encode (8 tiles of 32 px per block) =====
  {
    float* tile = (float*)SM;                // [32][257]
    float* partial = (float*)(SM + 32896);   // [8][32]
    float* inv = (float*)(SM + 33920);       // [32]
    for (int tt = 0; tt < 8; ++tt) {
      int tid4 = bid * 8 + tt;               // 4096 tiles
      int row = tid4 >> 3;
      int w0 = (tid4 & 7) * 32;
      int b = row >> 8, h = row & 255;
      const float* repb = rep + (size_t)b * CCH * HW + (size_t)h * 256 + w0;
      int w4 = t & 7, cbase = t >> 3;
#pragma unroll
      for (int it = 0; it < 8; ++it) {
        int c = it * 32 + cbase;
        float4 v = *(const float4*)&repb[(size_t)c * HW + w4 * 4];
        tile[(w4 * 4 + 0) * 257 + c] = v.x;
        tile[(w4 * 4 + 1) * 257 + c] = v.y;
        tile[(w4 * 4 + 2) * 257 + c] = v.z;
        tile[(w4 * 4 + 3) * 257 + c] = v.w;
      }
      __syncthreads();
      {
        int w = t & 31, qtr = t >> 5;
        float acc = 0.f;
#pragma unroll 8
        for (int cc = 0; cc < 32; ++cc) {
          float v = tile[w * 257 + qtr * 32 + cc];
          acc += v * v;
        }
        partial[qtr * 32 + w] = acc;
      }
      __syncthreads();
      if (t < 32) {
        float s = 0.f;
#pragma unroll
        for (int j = 0; j < 8; ++j) s += partial[j * 32 + t];
        float nm = fmaxf(sqrtf(s), 1e-8f);
        inv[t] = 1.0f / nm;
        norms[row * 256 + w0 + t] = nm;
      }
      __syncthreads();
      {
        int px = t & 31, chunk = t >> 5;     // chunk 0..7 (32 ch each)
        float iv = inv[px];
        size_t n = (size_t)(row * 256 + w0 + px);
#pragma unroll
        for (int hk = 0; hk < 2; ++hk) {
          float v[16];
#pragma unroll
          for (int k = 0; k < 16; ++k)
            v[k] = tile[px * 257 + chunk * 32 + hk * 16 + k] * iv;
          uint4 o;
          o.x = pack4fp8(v[0], v[1], v[2], v[3]);
          o.y = pack4fp8(v[4], v[5], v[6], v[7]);
          o.z = pack4fp8(v[8], v[9], v[10], v[11]);
          o.w = pack4fp8(v[12], v[13], v[14], v[15]);
          *(uint4*)&f8[n * CCH + chunk * 32 + hk * 16] = o;
        }
      }
      __syncthreads();
    }
  }
  __threadfence();
  grid.sync();

  // ===== P5: prototype sums from f8*norm over segment-sorted list =====
  {
    uint8_t* rows = (uint8_t*)SM;            // [64][256]
    float* nrm = (float*)(SM + 16384);       // [64]
    int* segs = (int*)(SM + 16640);          // [256]
    int* pixs = (int*)(SM + 17664);          // [256]
    float* red = (float*)(SM + 18688);       // [64][17]
    int base = bid * 256;
    int total = offs[NSEG];
    {
      int pos = base + t;
      int p = (pos < total) ? (list[pos] & (NPIX - 1)) : -1;
      pixs[t] = p;
      segs[t] = (p >= 0) ? (labh[p] & 31) : -1;
    }
    __syncthreads();
    int d = t & 63, qt = t >> 6;
    float a0 = 0.f, a1 = 0.f, a2 = 0.f, a3 = 0.f;
    int cseg = -2;
    for (int sub = 0; sub < 4; ++sub) {
      {
        int r = t >> 2, c = (t & 3) * 64;
        int p = pixs[sub * 64 + r];
        uint4* dst = (uint4*)&rows[r * 256 + c];
        if (p >= 0) {
          const uint4* src = (const uint4*)&f8[(size_t)p * CCH + c];
          dst[0] = src[0]; dst[1] = src[1]; dst[2] = src[2]; dst[3] = src[3];
        } else {
          uint4 z = make_uint4(0, 0, 0, 0);
          dst[0] = z; dst[1] = z; dst[2] = z; dst[3] = z;
        }
        if (t < 64) {
          int pp = pixs[sub * 64 + t];
          nrm[t] = (pp >= 0) ? norms[pp] : 0.f;
        }
      }
      __syncthreads();
      for (int pp = 0; pp < 16; ++pp) {
        int pl = qt * 16 + pp;
        int sg = segs[sub * 64 + pl];
        if (sg >= 0) {
          if (sg != cseg) {
            if (cseg >= 0) {
              atomicAdd(&proto[cseg * CCH + d * 4 + 0], a0);
              atomicAdd(&proto[cseg * CCH + d * 4 + 1], a1);
              atomicAdd(&proto[cseg * CCH + d * 4 + 2], a2);
              atomicAdd(&proto[cseg * CCH + d * 4 + 3], a3);
            }
            a0 = a1 = a2 = a3 = 0.f;
            cseg = sg;
          }
          uint32_t w = *(const uint32_t*)&rows[pl * 256 + d * 4];
          f32x2 lo = __builtin_amdgcn_cvt_pk_f32_fp8((int)w, false);
          f32x2 hi = __builtin_amdgcn_cvt_pk_f32_fp8((int)w, true);
          float nv = nrm[pl];
          a0 += lo.x * nv; a1 += lo.y * nv; a2 += hi.x * nv; a3 += hi.y * nv;
        }
      }
      __syncthreads();
    }
    int s0 = segs[0];
    int uni = __syncthreads_and((cseg < 0) || (cseg == s0));
    if (uni) {
      if (cseg >= 0) {
        red[d * 17 + qt * 4 + 0] = a0;
        red[d * 17 + qt * 4 + 1] = a1;
        red[d * 17 + qt * 4 + 2] = a2;
        red[d * 17 + qt * 4 + 3] = a3;
      }
      __syncthreads();
      if (t < 64 && s0 >= 0) {
#pragma unroll
        for (int c = 0; c < 4; ++c) {
          float v = red[t * 17 + 0 + c] + red[t * 17 + 4 + c]
                  + red[t * 17 + 8 + c] + red[t * 17 + 12 + c];
          atomicAdd(&proto[s0 * CCH + t * 4 + c], v);
        }
      }
    } else if (cseg >= 0) {
      atomicAdd(&proto[cseg * CCH + d * 4 + 0], a0);
      atomicAdd(&proto[cseg * CCH + d * 4 + 1], a1);
      atomicAdd(&proto[cseg * CCH + d * 4 + 2], a2);
      atomicAdd(&proto[cseg * CCH + d * 4 + 3], a3);
    }
  }
  __threadfence();
  grid.sync();

  // ===== P6: proto mean/normalize + CDFs (block 0) =====
  if (bid == 0) {
    float* pn = (float*)SM;                  // [21]
    float* spN = (float*)(SM + 96);          // [21*256]
    float* lg = (float*)(SM + 96 + 21504);   // [21][20]
    for (int idx = t; idx < NSEG * CCH; idx += 256) {
      int s = idx >> 8;
      int c = counts[s]; if (c < 1) c = 1;
      proto[idx] = proto[idx] / (float)c;
    }
    __syncthreads();
    if (t < NSEG) {
      float s2 = 0.f;
      for (int c = 0; c < CCH; ++c) { float v = proto[t * CCH + c]; s2 += v * v; }
      pn[t] = fmaxf(sqrtf(s2), 1e-8f);
    }
    __syncthreads();
    for (int idx = t; idx < NSEG * CCH; idx += 256) {
      int s = idx >> 8;
      float v = proto[idx] / pn[s];
      spN[idx] = v;
      protoN[idx] = v;
    }
    __syncthreads();
    for (int idx = t; idx < NSEG * NROLL; idx += 256) {
      int i = idx / NROLL, k = idx % NROLL;
      int j = (i + 1 + k) % NSEG;
      float d = 0.f;
      for (int c = 0; c < CCH; ++c) d += spN[i * CCH + c] * spN[j * CCH + c];
      lg[i * NROLL + k] = d * 2.0f;   // /TEMP
    }
    __syncthreads();
    if (t < NSEG) {
      float mx = -1e30f;
      for (int k = 0; k < NROLL; ++k) mx = fmaxf(mx, lg[t * NROLL + k]);
      float e[NROLL]; float s = 0.f;
      for (int k = 0; k < NROLL; ++k) { e[k] = __expf(lg[t * NROLL + k] - mx); s += e[k]; }
      float a = 0.f;
      for (int k = 0; k < NROLL; ++k) { a += e[k] / s; cdf[t * NROLL + k] = a; }
      cdf[t * NROLL + NROLL - 1] = 2.0f;
    }
  }
  __threadfence();
  grid.sync();

  // ===== P7: contrastive CE (672 units over 512 blocks) =====
  {
    half2t* anch = (half2t*)SM;              // 8*128
    float* pNs = (float*)(SM + 4096);        // [256]
    float* lgts = (float*)(SM + 5120);       // [8][264]
    float* s_cdf = (float*)(SM + 13568);     // [20]
    int* s_off = (int*)(SM + 13664);         // [21]
    int* s_cnt = (int*)(SM + 13760);         // [21]
    int* s_pidx = (int*)(SM + 13856);        // [256]
    int* s_apix = (int*)(SM + 14880);        // [8]
    float* s_ce = (float*)(SM + 14912);      // [8]

    for (int u = bid; u < NSEG * 32; u += NBLK) {
      int i = u >> 5, qc = u & 31;
      __syncthreads();
      if (t < NSEG) { s_off[t] = offs[t]; s_cnt[t] = counts[t]; }
      if (t < NROLL) s_cdf[t] = cdf[i * NROLL + t];
      pNs[t] = protoN[i * CCH + t];
      if (t < 8) {
        int q = qc * 8 + t;
        uint64_t r = rng64(i, q, 511u);
        int hc = hardc[i]; if (hc < 1) hc = 1;
        uint32_t jj = (uint32_t)(r & 0xffffffffu) % (uint32_t)hc;
        int idx = offs[i] + (int)jj;
        if (idx > NPIX - 1) idx = NPIX - 1;
        s_apix[t] = list[idx] & (NPIX - 1);
      }
      __syncthreads();
      {
        uint64_t r = rng64(i, 0u, (uint32_t)(t + 1));
        float u1 = (float)(r >> 40) * (1.0f / 16777216.0f);
        float u2 = (float)((r >> 16) & 0xFFFFFFu) * (1.0f / 16777216.0f);
        int k = 0;
#pragma unroll
        for (int kk = 0; kk < NROLL - 1; ++kk) k += (u1 >= s_cdf[kk]);
        int seg = i + 1 + k; if (seg >= NSEG) seg -= NSEG;
        int cnt = s_cnt[seg]; int cm = cnt < 1 ? 1 : cnt;
        int pidx = (int)(u2 * (float)cm);
        if (pidx > cm - 1) pidx = cm - 1;
        int li = s_off[seg] + pidx;
        if (li > NPIX - 1) li = NPIX - 1;
        s_pidx[t] = list[li] & (NPIX - 1);
      }
      if (t < 128) {
        int g = t >> 4, x = t & 15;
        uint4 w = *(const uint4*)&f8[(size_t)s_apix[g] * CCH + x * 16];
        half2t dx[8]; dec16(w, dx);
#pragma unroll
        for (int k = 0; k < 8; ++k) anch[g * 128 + x * 8 + k] = dx[k];
      }
      __syncthreads();

      const uint4* rowp = (const uint4*)&f8[(size_t)s_pidx[t] * CCH];
      float acc[8];
#pragma unroll
      for (int q = 0; q < 8; ++q) acc[q] = 0.f;
      for (int k0 = 0; k0 < 16; k0 += 4) {
        uint4 w4[4];
#pragma unroll
        for (int v = 0; v < 4; ++v) w4[v] = rowp[k0 + v];
#pragma unroll
        for (int v = 0; v < 4; ++v) {
          half2t nx[8]; dec16(w4[v], nx);
          const half2t* ar = anch + (k0 + v) * 8;
#pragma unroll
          for (int q = 0; q < 8; ++q) {
            const half2t* a = ar + q * 128;
            float s = acc[q];
#pragma unroll
            for (int k = 0; k < 8; ++k) s = fdot2h(a[k], nx[k], s);
            acc[q] = s;
          }
        }
      }
      float ps = 0.f;
      if (t < 128) {
        int g = t >> 4, x = t & 15;
#pragma unroll
        for (int k = 0; k < 8; ++k) {
          half2t a = anch[g * 128 + x * 8 + k];
          ps += (float)a.x * pNs[x * 16 + 2 * k] + (float)a.y * pNs[x * 16 + 2 * k + 1];
        }
#pragma unroll
        for (int o = 1; o <= 8; o <<= 1) ps += __shfl_xor(ps, o);
      }
#pragma unroll
      for (int q = 0; q < 8; ++q) lgts[q * 264 + 1 + t] = acc[q] * 2.0f;   // /TEMP
      if (t < 128 && (t & 15) == 0) lgts[(t >> 4) * 264] = ps * 2.0f;
      __syncthreads();

      int wave = t >> 6, lane = t & 63;
      for (int q = wave; q < 8; q += 4) {
        const float* L = lgts + q * 264;
        float v0 = L[lane], v1 = L[lane + 64], v2 = L[lane + 128], v3 = L[lane + 192];
        float v4 = (lane == 0) ? L[256] : -1e30f;
        float m = fmaxf(fmaxf(fmaxf(v0, v1), fmaxf(v2, v3)), v4);
#pragma unroll
        for (int o = 32; o >= 1; o >>= 1) m = fmaxf(m, __shfl_xor(m, o));
        float e = __expf(v0 - m) + __expf(v1 - m) + __expf(v2 - m) + __expf(v3 - m)
                + ((lane == 0) ? __expf(v4 - m) : 0.f);
#pragma unroll
        for (int o = 32; o >= 1; o >>= 1) e += __shfl_xor(e, o);
        if (lane == 0) s_ce[q] = m + logf(e) - L[0];
      }
      __syncthreads();
      if (t == 0) {
        float s = 0.f;
#pragma unroll
        for (int q = 0; q < 8; ++q) s += s_ce[q];
        atomicAdd(&seg_sum[i], s);
      }
    }
  }
  __threadfence();
  grid.sync();

  // ===== P8: final scalar =====
  if (bid == 0 && t == 0) {
    float tot = 0.f; int vs = 0;
    for (int s = 0; s < NSEG; ++s) {
      vs += (counts[s] > 0);
      if (hardc[s] > 0) tot += seg_sum[s];
    }
    float loss = (tot * (1.0f / 256.0f)) / (float)(vs > 0 ? vs : 1);
    out[0] = (vs > 1) ? loss : 0.f;
  }
}

extern "C" void kernel_launch(void* const* d_in, const int* in_sizes, int n_in,
                              void* d_out, int out_size, void* d_ws, size_t ws_size,
                              hipStream_t stream) {
  const float* rep   = (const float*)d_in[0];
  const int*   label = (const int*)d_in[1];
  const float* mask  = (const float*)d_in[2];
  const float* prob  = (const float*)d_in[3];

  char* ws = (char*)d_ws;
  uint8_t* f8 = (uint8_t*)ws;                            // 33,554,432 B (fp8 feats)
  size_t o = 67108864;
  float* norms  = (float*)(ws + o); o += 524288;
  int*   list   = (int*)(ws + o);   o += 524288;
  int*   labh   = (int*)(ws + o);   o += 524288;
  float* proto  = (float*)(ws + o); o += 21504;          // zero-region start
  float* segsum = (float*)(ws + o); o += 128;            // zero-region end
  int*   ticket = (int*)(ws + o);   o += 128;            // (unused)
  int*   counts = (int*)(ws + o);   o += 128;
  int*   hardc  = (int*)(ws + o);   o += 128;
  int*   offs   = (int*)(ws + o);   o += 128;            // offs[21]=total
  int*   cur_h  = (int*)(ws + o);   o += 128;
  int*   cur_e  = (int*)(ws + o);   o += 128;
  float* protoN = (float*)(ws + o); o += 21504;
  float* cdf    = (float*)(ws + o); o += 2048;
  int*   bc     = (int*)(ws + o);   o += 98304;          // 48 cols x 512 rows
  (void)ticket;

  float* outp = (float*)d_out;
  void* args[] = { (void*)&rep, (void*)&label, (void*)&mask, (void*)&prob,
                   (void*)&f8, (void*)&norms, (void*)&labh, (void*)&list,
                   (void*)&bc, (void*)&proto, (void*)&protoN, (void*)&counts,
                   (void*)&hardc, (void*)&offs, (void*)&cur_h, (void*)&cur_e,
                   (void*)&cdf, (void*)&segsum, (void*)&outp };
  (void)hipLaunchCooperativeKernel((const void*)reco_mega, dim3(NBLK), dim3(256),
                                   args, 0, stream);
}

// Round 16
// 106.596 us; speedup vs baseline: 7.5199x; 7.5199x over previous
//
#include <hip/hip_runtime.h>
#include <stdint.h>

#define NPIX  131072      // B*H*W = 2*256*256
#define HW    65536       // H*W
#define CCH   256         // channels
#define NSEG  21
#define NROLL 20          // NSEG-1

typedef float f32x2 __attribute__((ext_vector_type(2)));
typedef __fp16 half2t __attribute__((ext_vector_type(2)));

// ---------- helpers ----------
__device__ __forceinline__ uint64_t rng64(uint32_t i, uint32_t q, uint32_t j) {
  uint64_t x = ((uint64_t)((i << 8) | q) << 32) | (uint64_t)(j * 0x9E3779B1u);
  x ^= 0xD1B54A32D192ED03ULL;
  x += 0x9E3779B97F4A7C15ULL;
  x = (x ^ (x >> 30)) * 0xBF58476D1CE4E5B9ULL;
  x = (x ^ (x >> 27)) * 0x94D049BB133111EBULL;
  return x ^ (x >> 31);
}

__device__ __forceinline__ float fdot2h(half2t a, half2t b, float c) {
  return __builtin_amdgcn_fdot2(a, b, c, false);
}

// decode 16 fp8 (one uint4) -> 8 half2 (fp8 e4m3 exact in f16; RTZ exact)
__device__ __forceinline__ void dec16(uint4 w, half2t* nx) {
  uint32_t dw[4] = { w.x, w.y, w.z, w.w };
#pragma unroll
  for (int d = 0; d < 4; ++d) {
    f32x2 lo = __builtin_amdgcn_cvt_pk_f32_fp8((int)dw[d], false);
    f32x2 hi = __builtin_amdgcn_cvt_pk_f32_fp8((int)dw[d], true);
    nx[d * 2 + 0] = __builtin_amdgcn_cvt_pkrtz(lo.x, lo.y);
    nx[d * 2 + 1] = __builtin_amdgcn_cvt_pkrtz(hi.x, hi.y);
  }
}

// ---------- A: fused k5f (bid<2048) + flags (bid>=2048) ----------
__global__ __launch_bounds__(256) void reco_a(
    const float* __restrict__ rep, const int* __restrict__ label,
    const float* __restrict__ mask, const float* __restrict__ prob,
    uint8_t* __restrict__ f8, float* __restrict__ norms,
    int* __restrict__ labh, int* __restrict__ bc, float4* __restrict__ zr) {
  int t = threadIdx.x;
  __shared__ __align__(16) char SM[68352];

  if (blockIdx.x < 2048) {
    // ----- k5f: transpose + norm + fp8 encode (identical to R14) -----
    float* tile = (float*)SM;                   // [64][257]
    float* partial = (float*)(SM + 65792);      // [4][64]
    float* inv = (float*)(SM + 66816);          // [64]
    int bid = blockIdx.x;
    int wtile = bid & 3;
    int row = bid >> 2;              // b*H + h
    int b = row >> 8, h = row & 255;
    int w0 = wtile * 64;

    const float* repb = rep + (size_t)b * CCH * HW + (size_t)h * 256 + w0;
    int w4 = t & 15, cbase = t >> 4;
#pragma unroll
    for (int it = 0; it < 16; ++it) {
      int c = it * 16 + cbase;
      float4 v = *(const float4*)&repb[(size_t)c * HW + w4 * 4];
      tile[(w4 * 4 + 0) * 257 + c] = v.x;
      tile[(w4 * 4 + 1) * 257 + c] = v.y;
      tile[(w4 * 4 + 2) * 257 + c] = v.z;
      tile[(w4 * 4 + 3) * 257 + c] = v.w;
    }
    __syncthreads();
    {
      int w = t & 63, qtr = t >> 6;
      float acc = 0.f;
#pragma unroll 8
      for (int cc = 0; cc < 64; ++cc) {
        float v = tile[w * 257 + qtr * 64 + cc];
        acc += v * v;
      }
      partial[qtr * 64 + w] = acc;
    }
    __syncthreads();
    if (t < 64) {
      float s = partial[0 * 64 + t] + partial[1 * 64 + t] + partial[2 * 64 + t] + partial[3 * 64 + t];
      float nm = fmaxf(sqrtf(s), 1e-8f);
      inv[t] = 1.0f / nm;
      norms[row * 256 + w0 + t] = nm;
    }
    __syncthreads();
    int pix = t & 7, chunk = t >> 3;
#pragma unroll
    for (int it = 0; it < 8; ++it) {
      int p = it * 8 + pix;
      float iv = inv[p];
      float v[8];
#pragma unroll
      for (int k = 0; k < 8; ++k) v[k] = tile[p * 257 + chunk * 8 + k] * iv;
      uint32_t lo = 0, hi = 0;
      lo = (uint32_t)__builtin_amdgcn_cvt_pk_fp8_f32(v[0], v[1], (int)lo, false);
      lo = (uint32_t)__builtin_amdgcn_cvt_pk_fp8_f32(v[2], v[3], (int)lo, true);
      hi = (uint32_t)__builtin_amdgcn_cvt_pk_fp8_f32(v[4], v[5], (int)hi, false);
      hi = (uint32_t)__builtin_amdgcn_cvt_pk_fp8_f32(v[6], v[7], (int)hi, true);
      size_t n = (size_t)(row * 256 + w0 + p);
      uint2 o; o.x = lo; o.y = hi;
      *(uint2*)&f8[n * CCH + chunk * 8] = o;
    }
  } else {
    // ----- flags: labels/mask/prob -> labh + col-major count partials + zeroing -----
    int row = blockIdx.x - 2048;     // b*H + h
    int b = row >> 8, h = row & 255;
    int n = row * 256 + t;
    if (row < 6) {                   // proto(21504B)+segsum(128B)+ticket(128B) = 1360 f4
      int idx = row * 256 + t;
      if (idx < 1360) zr[idx] = make_float4(0.f, 0.f, 0.f, 0.f);
    }
    int lab = label[n];
    bool ignore = lab > NSEG - 1;
    if (ignore) lab = 0;
    float mval = ignore ? 0.f : mask[n];
    bool valid = mval > 0.f;
    float p_lab = prob[(((size_t)b * NSEG + lab) * 256 + h) * 256 + t];
    bool hard = valid && (p_lab < 1.0f);
    labh[n] = lab | (hard ? 32 : 0) | (valid ? 64 : 0);

    int* cpart = (int*)SM;
    int* hpart = (int*)SM + 24;
    if (t < NSEG) { cpart[t] = 0; hpart[t] = 0; }
    __syncthreads();
    if (valid) { atomicAdd(&cpart[lab], 1); if (hard) atomicAdd(&hpart[lab], 1); }
    __syncthreads();
    if (t < NSEG) {
      bc[t * 512 + row] = cpart[t];
      bc[(24 + t) * 512 + row] = hpart[t];
    }
  }
}

// ---------- K2t: reduce partials (one wave per column, coalesced) + offsets ----------
__global__ __launch_bounds__(256) void reco_k2t(
    const int* __restrict__ bc, int* __restrict__ counts, int* __restrict__ hardc,
    int* __restrict__ offs, int* __restrict__ cur_h, int* __restrict__ cur_e) {
  int t = threadIdx.x;
  int wave = t >> 6, lane = t & 63;
  __shared__ int sums[42];
  for (int c = wave; c < 42; c += 4) {
    int col = (c < 21) ? c : c + 3;
    const int* p = bc + col * 512 + lane * 8;
    int s = 0;
#pragma unroll
    for (int j = 0; j < 8; ++j) s += p[j];
#pragma unroll
    for (int o = 32; o >= 1; o >>= 1) s += __shfl_xor(s, o);
    if (lane == 0) sums[c] = s;
  }
  __syncthreads();
  if (t == 0) {
    int o = 0;
    for (int s = 0; s < NSEG; ++s) {
      counts[s] = sums[s];
      hardc[s] = sums[21 + s];
      offs[s] = o;
      cur_h[s] = o;
      cur_e[s] = o + sums[21 + s];
      o += sums[s];
    }
    offs[NSEG] = o;
  }
}

// ---------- K3: segment-grouped pixel list, hard-first; two-level ranking ----------
__global__ __launch_bounds__(256) void reco_k3(const int* __restrict__ labh,
                        int* __restrict__ cur_h, int* __restrict__ cur_e, int* __restrict__ list) {
  int t = threadIdx.x;
  int n = blockIdx.x * 256 + t;
  __shared__ int lcnt[2 * NSEG];
  __shared__ int lbase[2 * NSEG];
  if (t < 2 * NSEG) lcnt[t] = 0;
  __syncthreads();
  int v = labh[n];
  int lab = v & 31;
  bool hard = (v & 32) != 0;
  bool valid = (v & 64) != 0;
  int bucket = lab + (hard ? 0 : NSEG);
  int rank = 0;
  if (valid) rank = atomicAdd(&lcnt[bucket], 1);
  __syncthreads();
  if (t < 2 * NSEG) {
    int c = lcnt[t];
    lbase[t] = c ? atomicAdd((t < NSEG) ? &cur_h[t] : &cur_e[t - NSEG], c) : 0;
  }
  __syncthreads();
  if (valid) list[lbase[bucket] + rank] = n;
}

// ---------- proto8: prototype sums from f8*norm, walking the segment-sorted list ----------
__global__ __launch_bounds__(256) void reco_proto8(
    const uint8_t* __restrict__ f8, const float* __restrict__ norms,
    const int* __restrict__ list, const int* __restrict__ labh,
    const int* __restrict__ offs, float* __restrict__ proto) {
  int t = threadIdx.x;
  int base = blockIdx.x * 256;
  int total = offs[NSEG];

  __shared__ uint8_t rows[64][256];
  __shared__ float nrm[64];
  __shared__ int segs[256];
  __shared__ int pixs[256];
  __shared__ float red[64][17];

  {
    int pos = base + t;
    int p = (pos < total) ? (list[pos] & (NPIX - 1)) : -1;
    pixs[t] = p;
    segs[t] = (p >= 0) ? (labh[p] & 31) : -1;
  }
  __syncthreads();

  int d = t & 63, qt = t >> 6;
  float a0 = 0.f, a1 = 0.f, a2 = 0.f, a3 = 0.f;
  int cseg = -2;

  for (int sub = 0; sub < 4; ++sub) {
    {
      int r = t >> 2, c = (t & 3) * 64;
      int p = pixs[sub * 64 + r];
      uint4* dst = (uint4*)&rows[r][c];
      if (p >= 0) {
        const uint4* src = (const uint4*)&f8[(size_t)p * CCH + c];
        dst[0] = src[0]; dst[1] = src[1]; dst[2] = src[2]; dst[3] = src[3];
      } else {
        uint4 z = make_uint4(0, 0, 0, 0);
        dst[0] = z; dst[1] = z; dst[2] = z; dst[3] = z;
      }
      if (t < 64) {
        int pp = pixs[sub * 64 + t];
        nrm[t] = (pp >= 0) ? norms[pp] : 0.f;
      }
    }
    __syncthreads();
    for (int pp = 0; pp < 16; ++pp) {
      int pl = qt * 16 + pp;
      int sg = segs[sub * 64 + pl];
      if (sg >= 0) {
        if (sg != cseg) {
          if (cseg >= 0) {
            atomicAdd(&proto[cseg * CCH + d * 4 + 0], a0);
            atomicAdd(&proto[cseg * CCH + d * 4 + 1], a1);
            atomicAdd(&proto[cseg * CCH + d * 4 + 2], a2);
            atomicAdd(&proto[cseg * CCH + d * 4 + 3], a3);
          }
          a0 = a1 = a2 = a3 = 0.f;
          cseg = sg;
        }
        uint32_t w = *(const uint32_t*)&rows[pl][d * 4];
        f32x2 lo = __builtin_amdgcn_cvt_pk_f32_fp8((int)w, false);
        f32x2 hi = __builtin_amdgcn_cvt_pk_f32_fp8((int)w, true);
        float nv = nrm[pl];
        a0 += lo.x * nv; a1 += lo.y * nv; a2 += hi.x * nv; a3 += hi.y * nv;
      }
    }
    __syncthreads();
  }

  int s0 = segs[0];
  int uni = __syncthreads_and((cseg < 0) || (cseg == s0));
  if (uni) {
    if (cseg >= 0) {
      red[d][qt * 4 + 0] = a0;
      red[d][qt * 4 + 1] = a1;
      red[d][qt * 4 + 2] = a2;
      red[d][qt * 4 + 3] = a3;
    }
    __syncthreads();
    if (t < 64 && s0 >= 0) {
#pragma unroll
      for (int c = 0; c < 4; ++c) {
        float v = red[t][0 + c] + red[t][4 + c] + red[t][8 + c] + red[t][12 + c];
        atomicAdd(&proto[s0 * CCH + t * 4 + c], v);
      }
    }
  } else if (cseg >= 0) {
    atomicAdd(&proto[cseg * CCH + d * 4 + 0], a0);
    atomicAdd(&proto[cseg * CCH + d * 4 + 1], a1);
    atomicAdd(&proto[cseg * CCH + d * 4 + 2], a2);
    atomicAdd(&proto[cseg * CCH + d * 4 + 3], a3);
  }
}

// ---------- K6r: inline proto-normalize + CDF (replaces k4 node), then CE ----------
__global__ __launch_bounds__(256) void reco_k6r(
    const uint8_t* __restrict__ f8, const int* __restrict__ list,
    const int* __restrict__ counts, const int* __restrict__ hardc,
    const int* __restrict__ offs, const float* __restrict__ proto,
    float* __restrict__ seg_sum, int* __restrict__ ticket, float* __restrict__ out) {
  int bid = blockIdx.x;
  int i  = bid >> 5;               // segment
  int qc = bid & 31;               // query octet
  int t = threadIdx.x;

  __shared__ float spN[NSEG * CCH];   // 21.5 KB
  __shared__ float pn[NSEG];
  __shared__ float lgrow[NROLL];
  __shared__ half2t anch[8 * 128];    // 4 KB
  __shared__ float lgts[8][264];      // 8.4 KB
  __shared__ float s_cdf[NROLL];
  __shared__ int s_off[NSEG], s_cnt[NSEG], s_pidx[256], s_apix[8];
  __shared__ float s_ce[8];
  __shared__ int s_last;

  if (t < NSEG) { s_off[t] = offs[t]; s_cnt[t] = counts[t]; }
  __syncthreads();

  // ---- inline k4: spN = (proto/cnt)/pn, same fp op order as the old kernel ----
  for (int idx = t; idx < NSEG * CCH; idx += 256) {
    int s = idx >> 8;
    int c = s_cnt[s]; if (c < 1) c = 1;
    spN[idx] = proto[idx] / (float)c;
  }
  __syncthreads();
  if (t < NSEG) {
    float s2 = 0.f;
    for (int c = 0; c < CCH; ++c) { float v = spN[t * CCH + c]; s2 += v * v; }
    pn[t] = fmaxf(sqrtf(s2), 1e-8f);
  }
  __syncthreads();
  for (int idx = t; idx < NSEG * CCH; idx += 256) {
    int s = idx >> 8;
    spN[idx] = spN[idx] / pn[s];
  }
  __syncthreads();
  if (t < NROLL) {                 // only row i of the logit matrix is needed
    int j = (i + 1 + t) % NSEG;
    float d = 0.f;
    for (int c = 0; c < CCH; ++c) d += spN[i * CCH + c] * spN[j * CCH + c];
    lgrow[t] = d * 2.0f;           // /TEMP
  }
  __syncthreads();
  if (t == 0) {
    float mx = -1e30f;
    for (int k = 0; k < NROLL; ++k) mx = fmaxf(mx, lgrow[k]);
    float e[NROLL]; float s = 0.f;
    for (int k = 0; k < NROLL; ++k) { e[k] = __expf(lgrow[k] - mx); s += e[k]; }
    float a = 0.f;
    for (int k = 0; k < NROLL; ++k) { a += e[k] / s; s_cdf[k] = a; }
    s_cdf[NROLL - 1] = 2.0f;       // sentinel
  }
  if (t < 8) {
    int q = qc * 8 + t;
    uint64_t r = rng64(i, q, 511u);
    int hc = hardc[i]; if (hc < 1) hc = 1;
    uint32_t jj = (uint32_t)(r & 0xffffffffu) % (uint32_t)hc;
    int idx = offs[i] + (int)jj;
    if (idx > NPIX - 1) idx = NPIX - 1;
    s_apix[t] = list[idx] & (NPIX - 1);
  }
  __syncthreads();

  // per-thread shared-negative sampling (q=0 stream)
  {
    uint64_t r = rng64(i, 0u, (uint32_t)(t + 1));
    float u1 = (float)(r >> 40) * (1.0f / 16777216.0f);
    float u2 = (float)((r >> 16) & 0xFFFFFFu) * (1.0f / 16777216.0f);
    int k = 0;
#pragma unroll
    for (int kk = 0; kk < NROLL - 1; ++kk) k += (u1 >= s_cdf[kk]);
    int seg = i + 1 + k; if (seg >= NSEG) seg -= NSEG;
    int cnt = s_cnt[seg]; int cm = cnt < 1 ? 1 : cnt;
    int pidx = (int)(u2 * (float)cm);
    if (pidx > cm - 1) pidx = cm - 1;
    int li = s_off[seg] + pidx;
    if (li > NPIX - 1) li = NPIX - 1;
    s_pidx[t] = list[li] & (NPIX - 1);
  }
  // anchors: gather + decode (8 queries x 16 lanes)
  if (t < 128) {
    int g = t >> 4, x = t & 15;
    uint4 w = *(const uint4*)&f8[(size_t)s_apix[g] * CCH + x * 16];
    half2t dx[8]; dec16(w, dx);
#pragma unroll
    for (int k = 0; k < 8; ++k) anch[g * 128 + x * 8 + k] = dx[k];
  }
  __syncthreads();

  // dots: thread t streams its own candidate row (4 contiguous 16B loads in flight)
  const uint4* rowp = (const uint4*)&f8[(size_t)s_pidx[t] * CCH];
  float acc[8];
#pragma unroll
  for (int q = 0; q < 8; ++q) acc[q] = 0.f;
  for (int k0 = 0; k0 < 16; k0 += 4) {
    uint4 w4[4];
#pragma unroll
    for (int u = 0; u < 4; ++u) w4[u] = rowp[k0 + u];
#pragma unroll
    for (int u = 0; u < 4; ++u) {
      half2t nx[8]; dec16(w4[u], nx);
      const half2t* ar = anch + (k0 + u) * 8;
#pragma unroll
      for (int q = 0; q < 8; ++q) {
        const half2t* a = ar + q * 128;
        float s = acc[q];
#pragma unroll
        for (int k = 0; k < 8; ++k) s = fdot2h(a[k], nx[k], s);
        acc[q] = s;
      }
    }
  }
  // proto logits (8 queries x 16 lanes); pNs = spN row i
  float ps = 0.f;
  if (t < 128) {
    int g = t >> 4, x = t & 15;
    const float* pNs = spN + i * CCH;
#pragma unroll
    for (int k = 0; k < 8; ++k) {
      half2t a = anch[g * 128 + x * 8 + k];
      ps += (float)a.x * pNs[x * 16 + 2 * k] + (float)a.y * pNs[x * 16 + 2 * k + 1];
    }
#pragma unroll
    for (int o = 1; o <= 8; o <<= 1) ps += __shfl_xor(ps, o);
  }

#pragma unroll
  for (int q = 0; q < 8; ++q) lgts[q][1 + t] = acc[q] * 2.0f;   // /TEMP
  if (t < 128 && (t & 15) == 0) lgts[t >> 4][0] = ps * 2.0f;
  __syncthreads();

  // per-query softmax CE (wave per query, 2 queries/wave)
  int wave = t >> 6, lane = t & 63;
  for (int q = wave; q < 8; q += 4) {
    const float* L = lgts[q];
    float v0 = L[lane], v1 = L[lane + 64], v2 = L[lane + 128], v3 = L[lane + 192];
    float v4 = (lane == 0) ? L[256] : -1e30f;
    float m = fmaxf(fmaxf(fmaxf(v0, v1), fmaxf(v2, v3)), v4);
#pragma unroll
    for (int o = 32; o >= 1; o >>= 1) m = fmaxf(m, __shfl_xor(m, o));
    float e = __expf(v0 - m) + __expf(v1 - m) + __expf(v2 - m) + __expf(v3 - m)
            + ((lane == 0) ? __expf(v4 - m) : 0.f);
#pragma unroll
    for (int o = 32; o >= 1; o >>= 1) e += __shfl_xor(e, o);
    if (lane == 0) s_ce[q] = m + logf(e) - L[0];
  }
  __syncthreads();
  if (t == 0) {
    float s = 0.f;
#pragma unroll
    for (int q = 0; q < 8; ++q) s += s_ce[q];
    atomicAdd(&seg_sum[i], s);
    __threadfence();
    int done = atomicAdd(ticket, 1);
    s_last = (done == NSEG * 32 - 1);
  }
  __syncthreads();
  if (s_last && t == 0) {          // folded K7
    __threadfence();
    float tot = 0.f; int vs = 0;
    for (int s = 0; s < NSEG; ++s) {
      vs += (counts[s] > 0);
      float v = atomicAdd(&seg_sum[s], 0.f);   // device-scope read
      if (hardc[s] > 0) tot += v;
    }
    float loss = (tot * (1.0f / 256.0f)) / (float)(vs > 0 ? vs : 1);
    out[0] = (vs > 1) ? loss : 0.f;
  }
}

extern "C" void kernel_launch(void* const* d_in, const int* in_sizes, int n_in,
                              void* d_out, int out_size, void* d_ws, size_t ws_size,
                              hipStream_t stream) {
  const float* rep   = (const float*)d_in[0];
  const int*   label = (const int*)d_in[1];
  const float* mask  = (const float*)d_in[2];
  const float* prob  = (const float*)d_in[3];

  char* ws = (char*)d_ws;
  uint8_t* f8 = (uint8_t*)ws;                            // 33,554,432 B (fp8 feats)
  size_t o = 67108864;
  float* norms  = (float*)(ws + o); o += 524288;
  int*   list   = (int*)(ws + o);   o += 524288;
  int*   labh   = (int*)(ws + o);   o += 524288;
  float* proto  = (float*)(ws + o); o += 21504;          // zero-region start
  float* segsum = (float*)(ws + o); o += 128;
  int*   ticket = (int*)(ws + o);   o += 128;            // zero-region end (21760 B)
  int*   counts = (int*)(ws + o);   o += 128;
  int*   hardc  = (int*)(ws + o);   o += 128;
  int*   offs   = (int*)(ws + o);   o += 128;            // offs[21]=total
  int*   cur_h  = (int*)(ws + o);   o += 128;
  int*   cur_e  = (int*)(ws + o);   o += 128;
  int*   bc     = (int*)(ws + o);   o += 98304;          // 48 cols x 512 rows (col-major)

  reco_a<<<2560, 256, 0, stream>>>(rep, label, mask, prob, f8, norms, labh, bc, (float4*)proto);
  reco_k2t<<<1, 256, 0, stream>>>(bc, counts, hardc, offs, cur_h, cur_e);
  reco_k3<<<512, 256, 0, stream>>>(labh, cur_h, cur_e, list);
  reco_proto8<<<512, 256, 0, stream>>>(f8, norms, list, labh, offs, proto);
  reco_k6r<<<NSEG * 32, 256, 0, stream>>>(f8, list, counts, hardc, offs, proto,
                                          segsum, ticket, (float*)d_out);
}

// Round 18
// 105.483 us; speedup vs baseline: 7.5992x; 1.0105x over previous
//
#include <hip/hip_runtime.h>
#include <stdint.h>

#define NPIX  131072      // B*H*W = 2*256*256
#define HW    65536       // H*W
#define CCH   256         // channels
#define NSEG  21
#define NROLL 20          // NSEG-1

typedef float f32x2 __attribute__((ext_vector_type(2)));
typedef __fp16 half2t __attribute__((ext_vector_type(2)));

// ---------- helpers ----------
__device__ __forceinline__ uint64_t rng64(uint32_t i, uint32_t q, uint32_t j) {
  uint64_t x = ((uint64_t)((i << 8) | q) << 32) | (uint64_t)(j * 0x9E3779B1u);
  x ^= 0xD1B54A32D192ED03ULL;
  x += 0x9E3779B97F4A7C15ULL;
  x = (x ^ (x >> 30)) * 0xBF58476D1CE4E5B9ULL;
  x = (x ^ (x >> 27)) * 0x94D049BB133111EBULL;
  return x ^ (x >> 31);
}

__device__ __forceinline__ float fdot2h(half2t a, half2t b, float c) {
  return __builtin_amdgcn_fdot2(a, b, c, false);
}

// decode 16 fp8 (one uint4) -> 8 half2 (fp8 e4m3 exact in f16; RTZ exact)
__device__ __forceinline__ void dec16(uint4 w, half2t* nx) {
  uint32_t dw[4] = { w.x, w.y, w.z, w.w };
#pragma unroll
  for (int d = 0; d < 4; ++d) {
    f32x2 lo = __builtin_amdgcn_cvt_pk_f32_fp8((int)dw[d], false);
    f32x2 hi = __builtin_amdgcn_cvt_pk_f32_fp8((int)dw[d], true);
    nx[d * 2 + 0] = __builtin_amdgcn_cvt_pkrtz(lo.x, lo.y);
    nx[d * 2 + 1] = __builtin_amdgcn_cvt_pkrtz(hi.x, hi.y);
  }
}

__device__ __forceinline__ uint32_t pack4fp8(float a, float b, float c, float d) {
  uint32_t w = 0;
  w = (uint32_t)__builtin_amdgcn_cvt_pk_fp8_f32(a, b, (int)w, false);
  w = (uint32_t)__builtin_amdgcn_cvt_pk_fp8_f32(c, d, (int)w, true);
  return w;
}

// ---------- A: fused k5f (bid<4096, 32-px tiles, 33KB LDS -> 4 blk/CU) + flags ----------
__global__ __launch_bounds__(256) void reco_a(
    const float* __restrict__ rep, const int* __restrict__ label,
    const float* __restrict__ mask, const float* __restrict__ prob,
    uint8_t* __restrict__ f8, float* __restrict__ norms,
    int* __restrict__ labh, int* __restrict__ bc, float4* __restrict__ zr) {
  int t = threadIdx.x;
  __shared__ __align__(16) char SM[34048];

  if (blockIdx.x < 4096) {
    // ----- k5f: 32-px tile (bit-exact tiling verified in R15 P4) -----
    float* tile = (float*)SM;                // [32][257]
    float* partial = (float*)(SM + 32896);   // [8][32]
    float* inv = (float*)(SM + 33920);       // [32]
    int bid = blockIdx.x;
    int row = bid >> 3;
    int w0 = (bid & 7) * 32;
    int b = row >> 8, h = row & 255;
    const float* repb = rep + (size_t)b * CCH * HW + (size_t)h * 256 + w0;
    int w4 = t & 7, cbase = t >> 3;
#pragma unroll
    for (int it = 0; it < 8; ++it) {
      int c = it * 32 + cbase;
      float4 v = *(const float4*)&repb[(size_t)c * HW + w4 * 4];
      tile[(w4 * 4 + 0) * 257 + c] = v.x;
      tile[(w4 * 4 + 1) * 257 + c] = v.y;
      tile[(w4 * 4 + 2) * 257 + c] = v.z;
      tile[(w4 * 4 + 3) * 257 + c] = v.w;
    }
    __syncthreads();
    {
      int w = t & 31, qtr = t >> 5;
      float acc = 0.f;
#pragma unroll 8
      for (int cc = 0; cc < 32; ++cc) {
        float v = tile[w * 257 + qtr * 32 + cc];
        acc += v * v;
      }
      partial[qtr * 32 + w] = acc;
    }
    __syncthreads();
    if (t < 32) {
      float s = 0.f;
#pragma unroll
      for (int j = 0; j < 8; ++j) s += partial[j * 32 + t];
      float nm = fmaxf(sqrtf(s), 1e-8f);
      inv[t] = 1.0f / nm;
      norms[row * 256 + w0 + t] = nm;
    }
    __syncthreads();
    {
      int px = t & 31, chunk = t >> 5;     // chunk 0..7 (32 ch each)
      float iv = inv[px];
      size_t n = (size_t)(row * 256 + w0 + px);
#pragma unroll
      for (int hk = 0; hk < 2; ++hk) {
        float v[16];
#pragma unroll
        for (int k = 0; k < 16; ++k)
          v[k] = tile[px * 257 + chunk * 32 + hk * 16 + k] * iv;
        uint4 o;
        o.x = pack4fp8(v[0], v[1], v[2], v[3]);
        o.y = pack4fp8(v[4], v[5], v[6], v[7]);
        o.z = pack4fp8(v[8], v[9], v[10], v[11]);
        o.w = pack4fp8(v[12], v[13], v[14], v[15]);
        *(uint4*)&f8[n * CCH + chunk * 32 + hk * 16] = o;
      }
    }
  } else {
    // ----- flags: labh + col-major count partials + zeroing -----
    int row = blockIdx.x - 4096;     // b*H + h
    int b = row >> 8, h = row & 255;
    int n = row * 256 + t;
    if (row < 6) {                   // proto(1344 f4)+segsum(8 f4)+ticket(8 f4)=1360 f4
      int idx = row * 256 + t;
      if (idx < 1360) zr[idx] = make_float4(0.f, 0.f, 0.f, 0.f);
    }
    int lab = label[n];
    bool ignore = lab > NSEG - 1;
    if (ignore) lab = 0;
    float mval = ignore ? 0.f : mask[n];
    bool valid = mval > 0.f;
    float p_lab = prob[(((size_t)b * NSEG + lab) * 256 + h) * 256 + t];
    bool hard = valid && (p_lab < 1.0f);
    labh[n] = lab | (hard ? 32 : 0) | (valid ? 64 : 0);

    int* cpart = (int*)SM;
    int* hpart = (int*)SM + 24;
    if (t < NSEG) { cpart[t] = 0; hpart[t] = 0; }
    __syncthreads();
    if (valid) { atomicAdd(&cpart[lab], 1); if (hard) atomicAdd(&hpart[lab], 1); }
    __syncthreads();
    if (t < NSEG) {
      bc[t * 512 + row] = cpart[t];
      bc[(24 + t) * 512 + row] = hpart[t];
    }
  }
}

// ---------- K2t: reduce partials (one wave per column, coalesced) + offsets ----------
__global__ __launch_bounds__(256) void reco_k2t(
    const int* __restrict__ bc, int* __restrict__ counts, int* __restrict__ hardc,
    int* __restrict__ offs, int* __restrict__ cur_h, int* __restrict__ cur_e) {
  int t = threadIdx.x;
  int wave = t >> 6, lane = t & 63;
  __shared__ int sums[42];
  for (int c = wave; c < 42; c += 4) {
    int col = (c < 21) ? c : c + 3;
    const int* p = bc + col * 512 + lane * 8;
    int s = 0;
#pragma unroll
    for (int j = 0; j < 8; ++j) s += p[j];
#pragma unroll
    for (int o = 32; o >= 1; o >>= 1) s += __shfl_xor(s, o);
    if (lane == 0) sums[c] = s;
  }
  __syncthreads();
  if (t == 0) {
    int o = 0;
    for (int s = 0; s < NSEG; ++s) {
      counts[s] = sums[s];
      hardc[s] = sums[21 + s];
      offs[s] = o;
      cur_h[s] = o;
      cur_e[s] = o + sums[21 + s];
      o += sums[s];
    }
    offs[NSEG] = o;
  }
}

// ---------- K3: segment-grouped pixel list, hard-first; two-level ranking ----------
__global__ __launch_bounds__(256) void reco_k3(const int* __restrict__ labh,
                        int* __restrict__ cur_h, int* __restrict__ cur_e, int* __restrict__ list) {
  int t = threadIdx.x;
  int n = blockIdx.x * 256 + t;
  __shared__ int lcnt[2 * NSEG];
  __shared__ int lbase[2 * NSEG];
  if (t < 2 * NSEG) lcnt[t] = 0;
  __syncthreads();
  int v = labh[n];
  int lab = v & 31;
  bool hard = (v & 32) != 0;
  bool valid = (v & 64) != 0;
  int bucket = lab + (hard ? 0 : NSEG);
  int rank = 0;
  if (valid) rank = atomicAdd(&lcnt[bucket], 1);
  __syncthreads();
  if (t < 2 * NSEG) {
    int c = lcnt[t];
    lbase[t] = c ? atomicAdd((t < NSEG) ? &cur_h[t] : &cur_e[t - NSEG], c) : 0;
  }
  __syncthreads();
  if (valid) list[lbase[bucket] + rank] = n;
}

// ---------- proto8: prototype sums from f8*norm, walking the segment-sorted list ----------
__global__ __launch_bounds__(256) void reco_proto8(
    const uint8_t* __restrict__ f8, const float* __restrict__ norms,
    const int* __restrict__ list, const int* __restrict__ labh,
    const int* __restrict__ offs, float* __restrict__ proto) {
  int t = threadIdx.x;
  int base = blockIdx.x * 256;
  int total = offs[NSEG];

  __shared__ uint8_t rows[64][256];
  __shared__ float nrm[64];
  __shared__ int segs[256];
  __shared__ int pixs[256];
  __shared__ float red[64][17];

  {
    int pos = base + t;
    int p = (pos < total) ? (list[pos] & (NPIX - 1)) : -1;
    pixs[t] = p;
    segs[t] = (p >= 0) ? (labh[p] & 31) : -1;
  }
  __syncthreads();

  int d = t & 63, qt = t >> 6;
  float a0 = 0.f, a1 = 0.f, a2 = 0.f, a3 = 0.f;
  int cseg = -2;

  for (int sub = 0; sub < 4; ++sub) {
    {
      int r = t >> 2, c = (t & 3) * 64;
      int p = pixs[sub * 64 + r];
      uint4* dst = (uint4*)&rows[r][c];
      if (p >= 0) {
        const uint4* src = (const uint4*)&f8[(size_t)p * CCH + c];
        dst[0] = src[0]; dst[1] = src[1]; dst[2] = src[2]; dst[3] = src[3];
      } else {
        uint4 z = make_uint4(0, 0, 0, 0);
        dst[0] = z; dst[1] = z; dst[2] = z; dst[3] = z;
      }
      if (t < 64) {
        int pp = pixs[sub * 64 + t];
        nrm[t] = (pp >= 0) ? norms[pp] : 0.f;
      }
    }
    __syncthreads();
    for (int pp = 0; pp < 16; ++pp) {
      int pl = qt * 16 + pp;
      int sg = segs[sub * 64 + pl];
      if (sg >= 0) {
        if (sg != cseg) {
          if (cseg >= 0) {
            atomicAdd(&proto[cseg * CCH + d * 4 + 0], a0);
            atomicAdd(&proto[cseg * CCH + d * 4 + 1], a1);
            atomicAdd(&proto[cseg * CCH + d * 4 + 2], a2);
            atomicAdd(&proto[cseg * CCH + d * 4 + 3], a3);
          }
          a0 = a1 = a2 = a3 = 0.f;
          cseg = sg;
        }
        uint32_t w = *(const uint32_t*)&rows[pl][d * 4];
        f32x2 lo = __builtin_amdgcn_cvt_pk_f32_fp8((int)w, false);
        f32x2 hi = __builtin_amdgcn_cvt_pk_f32_fp8((int)w, true);
        float nv = nrm[pl];
        a0 += lo.x * nv; a1 += lo.y * nv; a2 += hi.x * nv; a3 += hi.y * nv;
      }
    }
    __syncthreads();
  }

  int s0 = segs[0];
  int uni = __syncthreads_and((cseg < 0) || (cseg == s0));
  if (uni) {
    if (cseg >= 0) {
      red[d][qt * 4 + 0] = a0;
      red[d][qt * 4 + 1] = a1;
      red[d][qt * 4 + 2] = a2;
      red[d][qt * 4 + 3] = a3;
    }
    __syncthreads();
    if (t < 64 && s0 >= 0) {
#pragma unroll
      for (int c = 0; c < 4; ++c) {
        float v = red[t][0 + c] + red[t][4 + c] + red[t][8 + c] + red[t][12 + c];
        atomicAdd(&proto[s0 * CCH + t * 4 + c], v);
      }
    }
  } else if (cseg >= 0) {
    atomicAdd(&proto[cseg * CCH + d * 4 + 0], a0);
    atomicAdd(&proto[cseg * CCH + d * 4 + 1], a1);
    atomicAdd(&proto[cseg * CCH + d * 4 + 2], a2);
    atomicAdd(&proto[cseg * CCH + d * 4 + 3], a3);
  }
}

// ---------- K6r: inline proto-normalize + CDF, then CE; folded final scalar ----------
__global__ __launch_bounds__(256) void reco_k6r(
    const uint8_t* __restrict__ f8, const int* __restrict__ list,
    const int* __restrict__ counts, const int* __restrict__ hardc,
    const int* __restrict__ offs, const float* __restrict__ proto,
    float* __restrict__ seg_sum, int* __restrict__ ticket, float* __restrict__ out) {
  int bid = blockIdx.x;
  int i  = bid >> 5;               // segment
  int qc = bid & 31;               // query octet
  int t = threadIdx.x;

  __shared__ float spN[NSEG * CCH];   // 21.5 KB
  __shared__ float pn[NSEG];
  __shared__ float lgrow[NROLL];
  __shared__ half2t anch[8 * 128];    // 4 KB
  __shared__ float lgts[8][264];      // 8.4 KB
  __shared__ float s_cdf[NROLL];
  __shared__ int s_off[NSEG], s_cnt[NSEG], s_pidx[256], s_apix[8];
  __shared__ float s_ce[8];
  __shared__ int s_last;

  if (t < NSEG) { s_off[t] = offs[t]; s_cnt[t] = counts[t]; }
  __syncthreads();

  // ---- inline k4: spN = (proto/cnt)/pn, same fp op order as before ----
  for (int idx = t; idx < NSEG * CCH; idx += 256) {
    int s = idx >> 8;
    int c = s_cnt[s]; if (c < 1) c = 1;
    spN[idx] = proto[idx] / (float)c;
  }
  __syncthreads();
  if (t < NSEG) {
    float s2 = 0.f;
    for (int c = 0; c < CCH; ++c) { float v = spN[t * CCH + c]; s2 += v * v; }
    pn[t] = fmaxf(sqrtf(s2), 1e-8f);
  }
  __syncthreads();
  for (int idx = t; idx < NSEG * CCH; idx += 256) {
    int s = idx >> 8;
    spN[idx] = spN[idx] / pn[s];
  }
  __syncthreads();
  if (t < NROLL) {                 // only row i of the logit matrix is needed
    int j = (i + 1 + t) % NSEG;
    float d = 0.f;
    for (int c = 0; c < CCH; ++c) d += spN[i * CCH + c] * spN[j * CCH + c];
    lgrow[t] = d * 2.0f;           // /TEMP
  }
  __syncthreads();
  if (t == 0) {
    float mx = -1e30f;
    for (int k = 0; k < NROLL; ++k) mx = fmaxf(mx, lgrow[k]);
    float e[NROLL]; float s = 0.f;
    for (int k = 0; k < NROLL; ++k) { e[k] = __expf(lgrow[k] - mx); s += e[k]; }
    float a = 0.f;
    for (int k = 0; k < NROLL; ++k) { a += e[k] / s; s_cdf[k] = a; }
    s_cdf[NROLL - 1] = 2.0f;       // sentinel
  }
  if (t < 8) {
    int q = qc * 8 + t;
    uint64_t r = rng64(i, q, 511u);
    int hc = hardc[i]; if (hc < 1) hc = 1;
    uint32_t jj = (uint32_t)(r & 0xffffffffu) % (uint32_t)hc;
    int idx = offs[i] + (int)jj;
    if (idx > NPIX - 1) idx = NPIX - 1;
    s_apix[t] = list[idx] & (NPIX - 1);
  }
  __syncthreads();

  // per-thread shared-negative sampling (q=0 stream)
  {
    uint64_t r = rng64(i, 0u, (uint32_t)(t + 1));
    float u1 = (float)(r >> 40) * (1.0f / 16777216.0f);
    float u2 = (float)((r >> 16) & 0xFFFFFFu) * (1.0f / 16777216.0f);
    int k = 0;
#pragma unroll
    for (int kk = 0; kk < NROLL - 1; ++kk) k += (u1 >= s_cdf[kk]);
    int seg = i + 1 + k; if (seg >= NSEG) seg -= NSEG;
    int cnt = s_cnt[seg]; int cm = cnt < 1 ? 1 : cnt;
    int pidx = (int)(u2 * (float)cm);
    if (pidx > cm - 1) pidx = cm - 1;
    int li = s_off[seg] + pidx;
    if (li > NPIX - 1) li = NPIX - 1;
    s_pidx[t] = list[li] & (NPIX - 1);
  }
  // anchors: gather + decode (8 queries x 16 lanes)
  if (t < 128) {
    int g = t >> 4, x = t & 15;
    uint4 w = *(const uint4*)&f8[(size_t)s_apix[g] * CCH + x * 16];
    half2t dx[8]; dec16(w, dx);
#pragma unroll
    for (int k = 0; k < 8; ++k) anch[g * 128 + x * 8 + k] = dx[k];
  }
  __syncthreads();

  // dots: thread t streams its own candidate row (4 contiguous 16B loads in flight)
  const uint4* rowp = (const uint4*)&f8[(size_t)s_pidx[t] * CCH];
  float acc[8];
#pragma unroll
  for (int q = 0; q < 8; ++q) acc[q] = 0.f;
  for (int k0 = 0; k0 < 16; k0 += 4) {
    uint4 w4[4];
#pragma unroll
    for (int u = 0; u < 4; ++u) w4[u] = rowp[k0 + u];
#pragma unroll
    for (int u = 0; u < 4; ++u) {
      half2t nx[8]; dec16(w4[u], nx);
      const half2t* ar = anch + (k0 + u) * 8;
#pragma unroll
      for (int q = 0; q < 8; ++q) {
        const half2t* a = ar + q * 128;
        float s = acc[q];
#pragma unroll
        for (int k = 0; k < 8; ++k) s = fdot2h(a[k], nx[k], s);
        acc[q] = s;
      }
    }
  }
  // proto logits (8 queries x 16 lanes); pNs = spN row i
  float ps = 0.f;
  if (t < 128) {
    int g = t >> 4, x = t & 15;
    const float* pNs = spN + i * CCH;
#pragma unroll
    for (int k = 0; k < 8; ++k) {
      half2t a = anch[g * 128 + x * 8 + k];
      ps += (float)a.x * pNs[x * 16 + 2 * k] + (float)a.y * pNs[x * 16 + 2 * k + 1];
    }
#pragma unroll
    for (int o = 1; o <= 8; o <<= 1) ps += __shfl_xor(ps, o);
  }

#pragma unroll
  for (int q = 0; q < 8; ++q) lgts[q][1 + t] = acc[q] * 2.0f;   // /TEMP
  if (t < 128 && (t & 15) == 0) lgts[t >> 4][0] = ps * 2.0f;
  __syncthreads();

  // per-query softmax CE (wave per query, 2 queries/wave)
  int wave = t >> 6, lane = t & 63;
  for (int q = wave; q < 8; q += 4) {
    const float* L = lgts[q];
    float v0 = L[lane], v1 = L[lane + 64], v2 = L[lane + 128], v3 = L[lane + 192];
    float v4 = (lane == 0) ? L[256] : -1e30f;
    float m = fmaxf(fmaxf(fmaxf(v0, v1), fmaxf(v2, v3)), v4);
#pragma unroll
    for (int o = 32; o >= 1; o >>= 1) m = fmaxf(m, __shfl_xor(m, o));
    float e = __expf(v0 - m) + __expf(v1 - m) + __expf(v2 - m) + __expf(v3 - m)
            + ((lane == 0) ? __expf(v4 - m) : 0.f);
#pragma unroll
    for (int o = 32; o >= 1; o >>= 1) e += __shfl_xor(e, o);
    if (lane == 0) s_ce[q] = m + logf(e) - L[0];
  }
  __syncthreads();
  if (t == 0) {
    float s = 0.f;
#pragma unroll
    for (int q = 0; q < 8; ++q) s += s_ce[q];
    atomicAdd(&seg_sum[i], s);
    __threadfence();
    int done = atomicAdd(ticket, 1);
    s_last = (done == NSEG * 32 - 1);   // ticket zeroed each call by reco_a
  }
  __syncthreads();
  if (s_last && t == 0) {          // folded K7
    __threadfence();
    float tot = 0.f; int vs = 0;
    for (int s = 0; s < NSEG; ++s) {
      vs += (counts[s] > 0);
      float v = atomicAdd(&seg_sum[s], 0.f);   // device-scope read
      if (hardc[s] > 0) tot += v;
    }
    float loss = (tot * (1.0f / 256.0f)) / (float)(vs > 0 ? vs : 1);
    out[0] = (vs > 1) ? loss : 0.f;
  }
}

extern "C" void kernel_launch(void* const* d_in, const int* in_sizes, int n_in,
                              void* d_out, int out_size, void* d_ws, size_t ws_size,
                              hipStream_t stream) {
  const float* rep   = (const float*)d_in[0];
  const int*   label = (const int*)d_in[1];
  const float* mask  = (const float*)d_in[2];
  const float* prob  = (const float*)d_in[3];

  char* ws = (char*)d_ws;
  uint8_t* f8 = (uint8_t*)ws;                            // 33,554,432 B (fp8 feats)
  size_t o = 67108864;
  float* norms  = (float*)(ws + o); o += 524288;
  int*   list   = (int*)(ws + o);   o += 524288;
  int*   labh   = (int*)(ws + o);   o += 524288;
  float* proto  = (float*)(ws + o); o += 21504;          // zero-region start
  float* segsum = (float*)(ws + o); o += 128;
  int*   ticket = (int*)(ws + o);   o += 128;            // zero-region end (21760 B)
  int*   counts = (int*)(ws + o);   o += 128;
  int*   hardc  = (int*)(ws + o);   o += 128;
  int*   offs   = (int*)(ws + o);   o += 128;            // offs[21]=total
  int*   cur_h  = (int*)(ws + o);   o += 128;
  int*   cur_e  = (int*)(ws + o);   o += 128;
  int*   bc     = (int*)(ws + o);   o += 98304;          // 48 cols x 512 rows (col-major)

  reco_a<<<4608, 256, 0, stream>>>(rep, label, mask, prob, f8, norms, labh, bc,
                                   (float4*)proto);
  reco_k2t<<<1, 256, 0, stream>>>(bc, counts, hardc, offs, cur_h, cur_e);
  reco_k3<<<512, 256, 0, stream>>>(labh, cur_h, cur_e, list);
  reco_proto8<<<512, 256, 0, stream>>>(f8, norms, list, labh, offs, proto);
  reco_k6r<<<NSEG * 32, 256, 0, stream>>>(f8, list, counts, hardc, offs, proto,
                                          segsum, ticket, (float*)d_out);
}